// Round 1
// baseline (100.458 us; speedup 1.0000x reference)
//
#include <hip/hip_runtime.h>

// ConvTranspose3d(3->16, k=3, s=2, p=1) + per-channel norm + 2x avgpool2 fused.
// y shape (32,16,63,63,63) never materialized.
// out = pooled 4x4x4 mean of normalized y -> (32,16,15,15,15)

#define N_BATCH 32
#define C_IN 3
#define C_OUT 16
#define D_Y 63
#define P_OUT 15
#define COUNT_Y 8001504.0f  // 32 * 63^3

// tap tables for local output offset lo in [0,4): (k, i_local) pairs
// lo=0: (k=1,i=0)          lo=1: (k=2,i=0),(k=0,i=1)
// lo=2: (k=1,i=1)          lo=3: (k=2,i=1),(k=0,i=2)
__device__ __constant__ const int c_dummy = 0; // (unused)

constexpr int NPAIR[4]  = {1, 2, 1, 2};
constexpr int PK[4][2]  = {{1, 1}, {2, 0}, {1, 1}, {2, 0}};
constexpr int PI[4][2]  = {{0, 0}, {0, 1}, {1, 1}, {1, 2}};

__global__ __launch_bounds__(256) void convt_pool_stats(
    const float* __restrict__ x,        // [32][3][32][32][32]
    const float* __restrict__ w,        // [3][16][3][3][3]
    float* __restrict__ pool,           // d_out: [32][16][15][15][15] raw 4^3 sums
    float* __restrict__ partials)       // ws: sums [8192], sumsq [8192]
{
    const int bx  = blockIdx.x;         // 0..15 == bd
    const int co  = blockIdx.y;         // 0..15
    const int n   = blockIdx.z;         // 0..31
    const int tid = threadIdx.x;
    const int bd = bx;
    const int bh = tid >> 4;            // 0..15
    const int bw = tid & 15;            // 0..15

    const int id0 = 2 * bd, ih0 = 2 * bh, iw0 = 2 * bw;
    const float* xn = x + (size_t)n * (C_IN * 32768);

    float y[4][4][4] = {};

    #pragma unroll
    for (int ci = 0; ci < 3; ++ci) {
        // weights for (ci, co): uniform across block -> scalar loads
        float wl[27];
        const float* wp = w + ((size_t)ci * C_OUT + co) * 27;
        #pragma unroll
        for (int k = 0; k < 27; ++k) wl[k] = wp[k];

        // 3x3x3 input patch (zero-padded past i=31)
        float xl[3][3][3];
        const float* xc = xn + (size_t)ci * 32768;
        #pragma unroll
        for (int dd = 0; dd < 3; ++dd) {
            const int id = id0 + dd;
            #pragma unroll
            for (int hh = 0; hh < 3; ++hh) {
                const int ih = ih0 + hh;
                #pragma unroll
                for (int ww = 0; ww < 3; ++ww) {
                    const int iw = iw0 + ww;
                    const bool v = (id < 32) && (ih < 32) && (iw < 32);
                    xl[dd][hh][ww] = v ? xc[(id * 32 + ih) * 32 + iw] : 0.0f;
                }
            }
        }

        // accumulate all 64 outputs, fully unrolled (static indices only)
        #pragma unroll
        for (int od = 0; od < 4; ++od) {
            #pragma unroll
            for (int pd = 0; pd < NPAIR[od]; ++pd) {
                const int kd = PK[od][pd], idd = PI[od][pd];
                #pragma unroll
                for (int oh = 0; oh < 4; ++oh) {
                    #pragma unroll
                    for (int ph = 0; ph < NPAIR[oh]; ++ph) {
                        const int kh = PK[oh][ph], ihh = PI[oh][ph];
                        #pragma unroll
                        for (int ow = 0; ow < 4; ++ow) {
                            #pragma unroll
                            for (int pw = 0; pw < NPAIR[ow]; ++pw) {
                                const int kw = PK[ow][pw], iww = PI[ow][pw];
                                y[od][oh][ow] = fmaf(wl[kd * 9 + kh * 3 + kw],
                                                     xl[idd][ihh][iww],
                                                     y[od][oh][ow]);
                            }
                        }
                    }
                }
            }
        }
    }

    // stats (mask o==63 which only occurs at block 15, local offset 3)
    const bool ed = (bd == 15), eh = (bh == 15), ew = (bw == 15);
    float s_sum = 0.0f, s_sq = 0.0f;
    #pragma unroll
    for (int od = 0; od < 4; ++od) {
        #pragma unroll
        for (int oh = 0; oh < 4; ++oh) {
            #pragma unroll
            for (int ow = 0; ow < 4; ++ow) {
                const float v = y[od][oh][ow];
                const bool valid = !((ed && od == 3) || (eh && oh == 3) || (ew && ow == 3));
                const float m = valid ? 1.0f : 0.0f;
                s_sum = fmaf(v, m, s_sum);
                s_sq  = fmaf(v * v, m, s_sq);
            }
        }
    }

    // pooled output (only interior blocks; there all 64 voxels are valid)
    if (!ed && !eh && !ew) {
        const int oidx = ((((n * C_OUT) + co) * P_OUT + bd) * P_OUT + bh) * P_OUT + bw;
        pool[oidx] = s_sum;
    }

    // block reduction: wave butterfly + LDS across 4 waves
    float r_sum = s_sum, r_sq = s_sq;
    #pragma unroll
    for (int m = 1; m < 64; m <<= 1) {
        r_sum += __shfl_xor(r_sum, m, 64);
        r_sq  += __shfl_xor(r_sq, m, 64);
    }
    __shared__ float red[8];
    const int wave = tid >> 6, lane = tid & 63;
    if (lane == 0) { red[wave] = r_sum; red[4 + wave] = r_sq; }
    __syncthreads();
    if (tid == 0) {
        const float ts = red[0] + red[1] + red[2] + red[3];
        const float tq = red[4] + red[5] + red[6] + red[7];
        const int pidx = (co * N_BATCH + n) * 16 + bx;   // co-major: [co][n][bx]
        partials[pidx] = ts;
        partials[8192 + pidx] = tq;
    }
}

__global__ __launch_bounds__(256) void finalize_stats(
    const float* __restrict__ partials,  // ws
    const float* __restrict__ gamma,
    const float* __restrict__ beta,
    float* __restrict__ ab)              // ws + 16384: a[16], b[16]
{
    const int c = blockIdx.x;            // 0..15
    const int tid = threadIdx.x;         // 256
    float s = 0.0f, q = 0.0f;
    #pragma unroll
    for (int j = tid; j < 512; j += 256) {
        s += partials[c * 512 + j];
        q += partials[8192 + c * 512 + j];
    }
    #pragma unroll
    for (int m = 1; m < 64; m <<= 1) {
        s += __shfl_xor(s, m, 64);
        q += __shfl_xor(q, m, 64);
    }
    __shared__ float red[8];
    const int wave = tid >> 6, lane = tid & 63;
    if (lane == 0) { red[wave] = s; red[4 + wave] = q; }
    __syncthreads();
    if (tid == 0) {
        const float ts = red[0] + red[1] + red[2] + red[3];
        const float tq = red[4] + red[5] + red[6] + red[7];
        const float mean = ts / COUNT_Y;
        const float var  = tq / COUNT_Y - mean * mean;
        const float invg = rsqrtf(var + 1e-5f) * gamma[c];
        ab[c]      = invg * (1.0f / 64.0f);
        ab[16 + c] = beta[c] - mean * invg;
    }
}

__global__ __launch_bounds__(256) void apply_norm(
    float* __restrict__ out, const float* __restrict__ ab)
{
    const int i = blockIdx.x * 256 + threadIdx.x;
    if (i >= N_BATCH * C_OUT * P_OUT * P_OUT * P_OUT) return;
    const int c = (i / (P_OUT * P_OUT * P_OUT)) & 15;
    out[i] = fmaf(out[i], ab[c], ab[16 + c]);
}

extern "C" void kernel_launch(void* const* d_in, const int* in_sizes, int n_in,
                              void* d_out, int out_size, void* d_ws, size_t ws_size,
                              hipStream_t stream) {
    const float* x     = (const float*)d_in[0];
    const float* w     = (const float*)d_in[1];
    const float* gamma = (const float*)d_in[2];
    const float* beta  = (const float*)d_in[3];
    float* out = (float*)d_out;
    float* ws  = (float*)d_ws;
    // ws layout (floats): [0,8192) block sums, [8192,16384) block sumsq,
    //                     [16384,16416) a[16],b[16]   -> 65,664 bytes total

    dim3 g1(16, 16, 32);
    convt_pool_stats<<<g1, 256, 0, stream>>>(x, w, out, ws);
    finalize_stats<<<16, 256, 0, stream>>>(ws, gamma, beta, ws + 16384);

    const int total = N_BATCH * C_OUT * P_OUT * P_OUT * P_OUT;  // 1,728,000
    apply_norm<<<(total + 255) / 256, 256, 0, stream>>>(out, ws + 16384);
}